// Round 2
// baseline (383.172 us; speedup 1.0000x reference)
//
#include <hip/hip_runtime.h>
#include <hip/hip_bf16.h>

// ExpertBank MoE FFN on gfx950 — round 2.
// Pipeline: zero -> count -> scan(padded offsets + loads output) -> assign(rowmap)
//           -> per segment: GEMM1(gelu->h bf16) -> GEMM2(scatter out).
// Segmentation adapts H footprint to ws_size (ws_size is constant across calls,
// so host-side branching on it is deterministic / capture-safe).
// ws layout: int[0..7] counts, int[8..15] cursors, int[16..23] offsets_pad,
//            int[32..32+9216) rowmap, byte 65536: H bf16 [9216/segs][2048].

typedef __bf16 bf16x8 __attribute__((ext_vector_type(8)));
typedef float f32x4 __attribute__((ext_vector_type(4)));

#define DM 512
#define DF 2048
#define NE 8
#define NTOK 4096
#define NPAIR 8192
#define HCAP 9216  // 72*128: capacity of 128-padded compact rows (8192 + 7*128 rounded up)

__device__ __forceinline__ unsigned short f2bf(float x) {
    // round-to-nearest-even bf16 (finite values only)
    unsigned u = __builtin_bit_cast(unsigned, x);
    return (unsigned short)((u + 0x7fffu + ((u >> 16) & 1u)) >> 16);
}
__device__ __forceinline__ unsigned pack2(float lo, float hi) {
    return (unsigned)f2bf(lo) | ((unsigned)f2bf(hi) << 16);
}
__device__ __forceinline__ float gelu_exact(float x) {
    return 0.5f * x * (1.0f + erff(x * 0.70710678118654752440f));
}

__global__ void k_zero(int* p) {
    if (threadIdx.x < 16) p[threadIdx.x] = 0;
}

__global__ void k_count(const int* __restrict__ sel, int* __restrict__ counts) {
    int p = blockIdx.x * blockDim.x + threadIdx.x;
    if (p < NPAIR) atomicAdd(&counts[sel[p]], 1);
}

__global__ void k_scan(const int* __restrict__ counts, int* __restrict__ opad,
                       float* __restrict__ loads_out) {
    if (threadIdx.x == 0) {
        int s = 0;
        for (int e = 0; e < NE; ++e) {
            opad[e] = s;
            s += (counts[e] + 127) & ~127;  // 128-align each expert's row range
            loads_out[e] = (float)counts[e] * (1.0f / (float)NTOK);
        }
    }
}

__global__ void k_assign(const int* __restrict__ sel, const int* __restrict__ opad,
                         int* __restrict__ cursors, int* __restrict__ rowmap) {
    int p = blockIdx.x * blockDim.x + threadIdx.x;
    if (p < NPAIR) {
        int e = sel[p];
        int pos = atomicAdd(&cursors[e], 1);
        rowmap[opad[e] + pos] = p;
    }
}

// ---------------- GEMM1: H[hrow, 0..2047] = gelu( x[tok(row)] @ W1[e] ), bf16 out ----
// block tile 128(M) x 128(N), BK=32, 4 waves (2x2), each wave 4x4 frags of 16x16x32.
// LDS tiles [128][40] bf16 (row pad to 80B: full-bank spread, 16B-aligned frag reads).
__launch_bounds__(256, 2)
__global__ void k_gemm1(const float* __restrict__ X, const float* __restrict__ W1,
                        const int* __restrict__ counts, const int* __restrict__ opad,
                        const int* __restrict__ rowmap, unsigned short* __restrict__ H,
                        int seg_lo, int seg_hi) {
    const int e = blockIdx.z, mt = blockIdx.y, nt = blockIdx.x;
    const int grow = opad[e] + mt * 128;           // global padded compact row of tile start
    if (grow < seg_lo || grow >= seg_hi) return;   // not this segment
    int valid = counts[e] - mt * 128;
    if (valid <= 0) return;
    if (valid > 128) valid = 128;
    const int hbase = grow - seg_lo;               // H row within this segment's buffer

    __shared__ __align__(16) unsigned short As[128 * 40];
    __shared__ __align__(16) unsigned short Bs[128 * 40];
    __shared__ int toks[128];

    const int tid = threadIdx.x;
    if (tid < 128) {
        int i = (tid < valid) ? tid : 0;
        toks[tid] = rowmap[grow + i] >> 1;  // pair -> token
    }
    __syncthreads();

    const int wave = tid >> 6, lane = tid & 63;
    const int wm = wave >> 1, wn = wave & 1;
    const int quad = lane >> 4, l15 = lane & 15;

    f32x4 acc[4][4] = {};

    const int arow = tid >> 1, ahalf = tid & 1;
    const int bn = tid & 127, bkh = tid >> 7;
    const float* xrow = X + (size_t)toks[arow] * DM + ahalf * 16;
    const float* w1p = W1 + (size_t)e * DM * DF + (size_t)(bkh * 16) * DF + (size_t)(nt * 128 + bn);

    for (int kt = 0; kt < DM / 32; ++kt) {
        const int k0 = kt * 32;
        // ---- stage A (gathered x rows, fp32 -> bf16) ----
        {
            const float4* src = (const float4*)(xrow + k0);
            float4 v0 = src[0], v1 = src[1], v2 = src[2], v3 = src[3];
            uint4 u0, u1;
            u0.x = pack2(v0.x, v0.y); u0.y = pack2(v0.z, v0.w);
            u0.z = pack2(v1.x, v1.y); u0.w = pack2(v1.z, v1.w);
            u1.x = pack2(v2.x, v2.y); u1.y = pack2(v2.z, v2.w);
            u1.z = pack2(v3.x, v3.y); u1.w = pack2(v3.z, v3.w);
            *(uint4*)&As[arow * 40 + ahalf * 16] = u0;
            *(uint4*)&As[arow * 40 + ahalf * 16 + 8] = u1;
        }
        // ---- stage B transposed: Bs[n][k] <- W1[e][k][n] ----
        {
            const float* g = w1p + (size_t)k0 * DF;
            float f[16];
#pragma unroll
            for (int kk = 0; kk < 16; ++kk) f[kk] = g[(size_t)kk * DF];
            uint4 u0, u1;
            u0.x = pack2(f[0], f[1]);  u0.y = pack2(f[2], f[3]);
            u0.z = pack2(f[4], f[5]);  u0.w = pack2(f[6], f[7]);
            u1.x = pack2(f[8], f[9]);  u1.y = pack2(f[10], f[11]);
            u1.z = pack2(f[12], f[13]); u1.w = pack2(f[14], f[15]);
            *(uint4*)&Bs[bn * 40 + bkh * 16] = u0;
            *(uint4*)&Bs[bn * 40 + bkh * 16 + 8] = u1;
        }
        __syncthreads();
        bf16x8 a[4], b[4];
#pragma unroll
        for (int fm = 0; fm < 4; ++fm)
            a[fm] = __builtin_bit_cast(bf16x8, *(const uint4*)&As[(wm * 64 + fm * 16 + l15) * 40 + quad * 8]);
#pragma unroll
        for (int fn = 0; fn < 4; ++fn)
            b[fn] = __builtin_bit_cast(bf16x8, *(const uint4*)&Bs[(wn * 64 + fn * 16 + l15) * 40 + quad * 8]);
#pragma unroll
        for (int fm = 0; fm < 4; ++fm)
#pragma unroll
            for (int fn = 0; fn < 4; ++fn)
                acc[fm][fn] = __builtin_amdgcn_mfma_f32_16x16x32_bf16(a[fm], b[fn], acc[fm][fn], 0, 0, 0);
        __syncthreads();
    }

    // epilogue: gelu -> bf16 h (segment-local compact row order)
#pragma unroll
    for (int fm = 0; fm < 4; ++fm) {
#pragma unroll
        for (int i = 0; i < 4; ++i) {
            int m_l = wm * 64 + fm * 16 + quad * 4 + i;
            if (m_l < valid) {
                unsigned short* hrow = H + (size_t)(hbase + m_l) * DF + nt * 128 + wn * 64;
#pragma unroll
                for (int fn = 0; fn < 4; ++fn)
                    hrow[fn * 16 + l15] = f2bf(gelu_exact(acc[fm][fn][i]));
            }
        }
    }
}

// ---------------- GEMM2: out[pair(row), 0..511] = h[row] @ W2[e], fp32 scatter -------
__launch_bounds__(256, 2)
__global__ void k_gemm2(const unsigned short* __restrict__ H, const float* __restrict__ W2,
                        const int* __restrict__ counts, const int* __restrict__ opad,
                        const int* __restrict__ rowmap, float* __restrict__ out,
                        int seg_lo, int seg_hi) {
    const int e = blockIdx.z, mt = blockIdx.y, nt = blockIdx.x;
    const int grow = opad[e] + mt * 128;
    if (grow < seg_lo || grow >= seg_hi) return;
    int valid = counts[e] - mt * 128;
    if (valid <= 0) return;
    if (valid > 128) valid = 128;
    const int hbase = grow - seg_lo;

    __shared__ __align__(16) unsigned short As[128 * 40];
    __shared__ __align__(16) unsigned short Bs[128 * 40];
    __shared__ int pairs[128];

    const int tid = threadIdx.x;
    if (tid < 128) pairs[tid] = (tid < valid) ? rowmap[grow + tid] : 0;
    __syncthreads();

    const int wave = tid >> 6, lane = tid & 63;
    const int wm = wave >> 1, wn = wave & 1;
    const int quad = lane >> 4, l15 = lane & 15;

    f32x4 acc[4][4] = {};

    const int bn = tid & 127, bkh = tid >> 7;
    const float* w2p = W2 + (size_t)e * DF * DM + (size_t)(bkh * 16) * DM + (size_t)(nt * 128 + bn);

    for (int kt = 0; kt < DF / 32; ++kt) {
        const int k0 = kt * 32;
        // ---- stage A: contiguous compact bf16 h rows, direct 16B copies ----
        for (int c = tid; c < 512; c += 256) {
            int row = c >> 2, sub = c & 3;
            int rr = (row < valid) ? row : 0;
            const uint4* src = (const uint4*)(H + (size_t)(hbase + rr) * DF + k0 + sub * 8);
            *(uint4*)&As[row * 40 + sub * 8] = *src;
        }
        // ---- stage B transposed: Bs[n][k] <- W2[e][k][n] ----
        {
            const float* g = w2p + (size_t)k0 * DM;
            float f[16];
#pragma unroll
            for (int kk = 0; kk < 16; ++kk) f[kk] = g[(size_t)kk * DM];
            uint4 u0, u1;
            u0.x = pack2(f[0], f[1]);  u0.y = pack2(f[2], f[3]);
            u0.z = pack2(f[4], f[5]);  u0.w = pack2(f[6], f[7]);
            u1.x = pack2(f[8], f[9]);  u1.y = pack2(f[10], f[11]);
            u1.z = pack2(f[12], f[13]); u1.w = pack2(f[14], f[15]);
            *(uint4*)&Bs[bn * 40 + bkh * 16] = u0;
            *(uint4*)&Bs[bn * 40 + bkh * 16 + 8] = u1;
        }
        __syncthreads();
        bf16x8 a[4], b[4];
#pragma unroll
        for (int fm = 0; fm < 4; ++fm)
            a[fm] = __builtin_bit_cast(bf16x8, *(const uint4*)&As[(wm * 64 + fm * 16 + l15) * 40 + quad * 8]);
#pragma unroll
        for (int fn = 0; fn < 4; ++fn)
            b[fn] = __builtin_bit_cast(bf16x8, *(const uint4*)&Bs[(wn * 64 + fn * 16 + l15) * 40 + quad * 8]);
#pragma unroll
        for (int fm = 0; fm < 4; ++fm)
#pragma unroll
            for (int fn = 0; fn < 4; ++fn)
                acc[fm][fn] = __builtin_amdgcn_mfma_f32_16x16x32_bf16(a[fm], b[fn], acc[fm][fn], 0, 0, 0);
        __syncthreads();
    }

    // epilogue: scatter fp32 rows to out by pair id
#pragma unroll
    for (int fm = 0; fm < 4; ++fm) {
#pragma unroll
        for (int i = 0; i < 4; ++i) {
            int m_l = wm * 64 + fm * 16 + quad * 4 + i;
            if (m_l < valid) {
                float* orow = out + (size_t)pairs[m_l] * DM + nt * 128 + wn * 64;
#pragma unroll
                for (int fn = 0; fn < 4; ++fn)
                    orow[fn * 16 + l15] = acc[fm][fn][i];
            }
        }
    }
}

extern "C" void kernel_launch(void* const* d_in, const int* in_sizes, int n_in,
                              void* d_out, int out_size, void* d_ws, size_t ws_size,
                              hipStream_t stream) {
    const float* X = (const float*)d_in[0];
    const int* sel = (const int*)d_in[1];
    // d_in[2] = expert_masks (unused by the reference math)
    const float* W1 = (const float*)d_in[3];
    const float* W2 = (const float*)d_in[4];
    float* out = (float*)d_out;
    float* loads_out = out + (size_t)NPAIR * DM;  // expert_outputs (4,194,304 floats) first

    int* counts = (int*)d_ws;
    int* cursors = counts + 8;
    int* opad = counts + 16;
    int* rowmap = counts + 32;
    unsigned short* H = (unsigned short*)((char*)d_ws + 65536);

    // Adapt H footprint to the (call-invariant) workspace size: segments of the
    // padded compact row space, each segment runs GEMM1 then GEMM2.
    int segs = 1;
    while (segs < 8 && (size_t)65536 + (size_t)(HCAP / segs) * DF * 2 > ws_size) segs <<= 1;
    const int segrows = HCAP / segs;

    hipLaunchKernelGGL(k_zero, dim3(1), dim3(64), 0, stream, counts);
    hipLaunchKernelGGL(k_count, dim3(NPAIR / 256), dim3(256), 0, stream, sel, counts);
    hipLaunchKernelGGL(k_scan, dim3(1), dim3(64), 0, stream, counts, opad, loads_out);
    hipLaunchKernelGGL(k_assign, dim3(NPAIR / 256), dim3(256), 0, stream, sel, opad, cursors, rowmap);

    for (int s = 0; s < segs; ++s) {
        const int lo = s * segrows, hi = lo + segrows;
        hipLaunchKernelGGL(k_gemm1, dim3(DF / 128, NPAIR / 128, NE), dim3(256), 0, stream,
                           X, W1, counts, opad, rowmap, H, lo, hi);
        hipLaunchKernelGGL(k_gemm2, dim3(DM / 128, NPAIR / 128, NE), dim3(256), 0, stream,
                           H, W2, counts, opad, rowmap, out, lo, hi);
    }
}

// Round 3
// 344.437 us; speedup vs baseline: 1.1125x; 1.1125x over previous
//
#include <hip/hip_runtime.h>
#include <hip/hip_bf16.h>

// ExpertBank MoE FFN on gfx950 — round 3.
// zero -> count -> scan -> assign -> GEMM1(gelu->H bf16) -> GEMM2(scatter out).
// Round-3 changes (latency attack): 3 blocks/CU, register-prefetch software
// pipeline in both GEMMs, gemm2 retiled to 128x64 (576 active blocks, full K).
// ws: int[0..7] counts, [8..15] cursors, [16..23] opad, [32..) rowmap(9216),
//     byte 65536: H bf16 [9216][2048] (37.8 MB; proven available in round 2).

typedef __bf16 bf16x8 __attribute__((ext_vector_type(8)));
typedef float f32x4 __attribute__((ext_vector_type(4)));

#define DM 512
#define DF 2048
#define NE 8
#define NTOK 4096
#define NPAIR 8192
#define HCAP 9216

__device__ __forceinline__ unsigned short f2bf(float x) {
    unsigned u = __builtin_bit_cast(unsigned, x);
    return (unsigned short)((u + 0x7fffu + ((u >> 16) & 1u)) >> 16);
}
__device__ __forceinline__ unsigned pack2(float lo, float hi) {
    return (unsigned)f2bf(lo) | ((unsigned)f2bf(hi) << 16);
}
__device__ __forceinline__ float gelu_exact(float x) {
    return 0.5f * x * (1.0f + erff(x * 0.70710678118654752440f));
}

__global__ void k_zero(int* p) {
    if (threadIdx.x < 16) p[threadIdx.x] = 0;
}

__global__ void k_count(const int* __restrict__ sel, int* __restrict__ counts) {
    int p = blockIdx.x * blockDim.x + threadIdx.x;
    if (p < NPAIR) atomicAdd(&counts[sel[p]], 1);
}

__global__ void k_scan(const int* __restrict__ counts, int* __restrict__ opad,
                       float* __restrict__ loads_out) {
    if (threadIdx.x == 0) {
        int s = 0;
        for (int e = 0; e < NE; ++e) {
            opad[e] = s;
            s += (counts[e] + 127) & ~127;
            loads_out[e] = (float)counts[e] * (1.0f / (float)NTOK);
        }
    }
}

__global__ void k_assign(const int* __restrict__ sel, const int* __restrict__ opad,
                         int* __restrict__ cursors, int* __restrict__ rowmap) {
    int p = blockIdx.x * blockDim.x + threadIdx.x;
    if (p < NPAIR) {
        int e = sel[p];
        int pos = atomicAdd(&cursors[e], 1);
        rowmap[opad[e] + pos] = p;
    }
}

// ---------------- GEMM1: H[row] = gelu( x[tok(row)] @ W1[e] ), 128x128 tile, BK=32 ---
// Software pipeline: global loads for kt+1 issued right after barrier1, consumed
// at kt+1's LDS store. LDS rows padded to 40 shorts (80 B) for bank spread.
__launch_bounds__(256, 3)
__global__ void k_gemm1(const float* __restrict__ X, const float* __restrict__ W1,
                        const int* __restrict__ counts, const int* __restrict__ opad,
                        const int* __restrict__ rowmap, unsigned short* __restrict__ H) {
    const int e = blockIdx.z, mt = blockIdx.y, nt = blockIdx.x;
    const int grow = opad[e] + mt * 128;
    int valid = counts[e] - mt * 128;
    if (valid <= 0) return;
    if (valid > 128) valid = 128;

    __shared__ __align__(16) unsigned short As[128 * 40];
    __shared__ __align__(16) unsigned short Bs[128 * 40];
    __shared__ int toks[128];

    const int tid = threadIdx.x;
    if (tid < 128) {
        int i = (tid < valid) ? tid : 0;
        toks[tid] = rowmap[grow + i] >> 1;
    }
    __syncthreads();

    const int wave = tid >> 6, lane = tid & 63;
    const int wm = wave >> 1, wn = wave & 1;
    const int quad = lane >> 4, l15 = lane & 15;

    f32x4 acc[4][4] = {};

    const int arow = tid >> 1, ahalf = tid & 1;
    const int bn = tid & 127, bkh = tid >> 7;
    const float* xrow = X + (size_t)toks[arow] * DM + ahalf * 16;
    const float* w1p = W1 + (size_t)e * DM * DF + (size_t)(bkh * 16) * DF + (size_t)(nt * 128 + bn);

    // ---- preload kt = 0 ----
    float4 av0, av1, av2, av3;
    float bf[16];
    {
        const float4* s = (const float4*)xrow;
        av0 = s[0]; av1 = s[1]; av2 = s[2]; av3 = s[3];
        const float* g = w1p;
#pragma unroll
        for (int kk = 0; kk < 16; ++kk) bf[kk] = g[(size_t)kk * DF];
    }

    for (int kt = 0; kt < DM / 32; ++kt) {
        // ---- store current regs -> LDS (fp32 -> bf16 pack) ----
        {
            uint4 u0, u1;
            u0.x = pack2(av0.x, av0.y); u0.y = pack2(av0.z, av0.w);
            u0.z = pack2(av1.x, av1.y); u0.w = pack2(av1.z, av1.w);
            u1.x = pack2(av2.x, av2.y); u1.y = pack2(av2.z, av2.w);
            u1.z = pack2(av3.x, av3.y); u1.w = pack2(av3.z, av3.w);
            *(uint4*)&As[arow * 40 + ahalf * 16] = u0;
            *(uint4*)&As[arow * 40 + ahalf * 16 + 8] = u1;
            uint4 w0, w1;
            w0.x = pack2(bf[0], bf[1]);   w0.y = pack2(bf[2], bf[3]);
            w0.z = pack2(bf[4], bf[5]);   w0.w = pack2(bf[6], bf[7]);
            w1.x = pack2(bf[8], bf[9]);   w1.y = pack2(bf[10], bf[11]);
            w1.z = pack2(bf[12], bf[13]); w1.w = pack2(bf[14], bf[15]);
            *(uint4*)&Bs[bn * 40 + bkh * 16] = w0;
            *(uint4*)&Bs[bn * 40 + bkh * 16 + 8] = w1;
        }
        __syncthreads();

        // ---- issue next k-tile's global loads (overlap with MFMA below) ----
        const int kn = (kt < DM / 32 - 1) ? kt + 1 : kt;
        float4 na0, na1, na2, na3;
        float nbf[16];
        {
            const float4* s = (const float4*)(xrow + kn * 32);
            na0 = s[0]; na1 = s[1]; na2 = s[2]; na3 = s[3];
            const float* g = w1p + (size_t)(kn * 32) * DF;
#pragma unroll
            for (int kk = 0; kk < 16; ++kk) nbf[kk] = g[(size_t)kk * DF];
        }

        bf16x8 a[4], b[4];
#pragma unroll
        for (int fm = 0; fm < 4; ++fm)
            a[fm] = __builtin_bit_cast(bf16x8, *(const uint4*)&As[(wm * 64 + fm * 16 + l15) * 40 + quad * 8]);
#pragma unroll
        for (int fn = 0; fn < 4; ++fn)
            b[fn] = __builtin_bit_cast(bf16x8, *(const uint4*)&Bs[(wn * 64 + fn * 16 + l15) * 40 + quad * 8]);
#pragma unroll
        for (int fm = 0; fm < 4; ++fm)
#pragma unroll
            for (int fn = 0; fn < 4; ++fn)
                acc[fm][fn] = __builtin_amdgcn_mfma_f32_16x16x32_bf16(a[fm], b[fn], acc[fm][fn], 0, 0, 0);
        __syncthreads();

        av0 = na0; av1 = na1; av2 = na2; av3 = na3;
#pragma unroll
        for (int kk = 0; kk < 16; ++kk) bf[kk] = nbf[kk];
    }

#pragma unroll
    for (int fm = 0; fm < 4; ++fm) {
#pragma unroll
        for (int i = 0; i < 4; ++i) {
            int m_l = wm * 64 + fm * 16 + quad * 4 + i;
            if (m_l < valid) {
                unsigned short* hrow = H + (size_t)(grow + m_l) * DF + nt * 128 + wn * 64;
#pragma unroll
                for (int fn = 0; fn < 4; ++fn)
                    hrow[fn * 16 + l15] = f2bf(gelu_exact(acc[fm][fn][i]));
            }
        }
    }
}

// ---------------- GEMM2: out[pair] = h[row] @ W2[e], tile 128(M) x 64(N), BK=32 ------
// 8 N-tiles -> ~576 active blocks (2.25/CU). 4 waves as 2x2, each 64x32 (4x2 frags).
__launch_bounds__(256, 3)
__global__ void k_gemm2(const unsigned short* __restrict__ H, const float* __restrict__ W2,
                        const int* __restrict__ counts, const int* __restrict__ opad,
                        const int* __restrict__ rowmap, float* __restrict__ out) {
    const int e = blockIdx.z, mt = blockIdx.y, nt = blockIdx.x;
    const int grow = opad[e] + mt * 128;
    int valid = counts[e] - mt * 128;
    if (valid <= 0) return;
    if (valid > 128) valid = 128;

    __shared__ __align__(16) unsigned short As[128 * 40];
    __shared__ __align__(16) unsigned short Bs[64 * 40];
    __shared__ int pairs[128];

    const int tid = threadIdx.x;
    if (tid < 128) pairs[tid] = (tid < valid) ? rowmap[grow + tid] : 0;
    __syncthreads();

    const int wave = tid >> 6, lane = tid & 63;
    const int wm = wave >> 1, wn = wave & 1;
    const int quad = lane >> 4, l15 = lane & 15;

    f32x4 acc[4][2] = {};

    // A staging: two (row,sub) 16B chunks per thread
    const int ar0 = tid >> 2, sub = tid & 3;          // rows 0..63
    const int ar1 = ar0 + 64;                          // rows 64..127
    const int rr0 = (ar0 < valid) ? ar0 : 0;
    const int rr1 = (ar1 < valid) ? ar1 : 0;
    const unsigned short* h0 = H + (size_t)(grow + rr0) * DF + sub * 8;
    const unsigned short* h1 = H + (size_t)(grow + rr1) * DF + sub * 8;
    // B staging: 8 strided floats per thread
    const int bn = tid & 63, bq = tid >> 6;            // bq in 0..3 -> k sub-range
    const float* w2p = W2 + (size_t)e * DF * DM + (size_t)(bq * 8) * DM + (size_t)(nt * 64 + bn);

    // ---- preload kt = 0 ----
    uint4 ha = *(const uint4*)h0;
    uint4 hb = *(const uint4*)h1;
    float bf[8];
    {
        const float* g = w2p;
#pragma unroll
        for (int kk = 0; kk < 8; ++kk) bf[kk] = g[(size_t)kk * DM];
    }

    for (int kt = 0; kt < DF / 32; ++kt) {
        // ---- store current regs -> LDS ----
        {
            *(uint4*)&As[ar0 * 40 + sub * 8] = ha;
            *(uint4*)&As[ar1 * 40 + sub * 8] = hb;
            uint4 w;
            w.x = pack2(bf[0], bf[1]); w.y = pack2(bf[2], bf[3]);
            w.z = pack2(bf[4], bf[5]); w.w = pack2(bf[6], bf[7]);
            *(uint4*)&Bs[bn * 40 + bq * 8] = w;
        }
        __syncthreads();

        // ---- issue next k-tile's global loads ----
        const int kn = (kt < DF / 32 - 1) ? kt + 1 : kt;
        uint4 nha = *(const uint4*)(h0 + kn * 32);
        uint4 nhb = *(const uint4*)(h1 + kn * 32);
        float nbf[8];
        {
            const float* g = w2p + (size_t)(kn * 32) * DM;
#pragma unroll
            for (int kk = 0; kk < 8; ++kk) nbf[kk] = g[(size_t)kk * DM];
        }

        bf16x8 a[4], b[2];
#pragma unroll
        for (int fm = 0; fm < 4; ++fm)
            a[fm] = __builtin_bit_cast(bf16x8, *(const uint4*)&As[(wm * 64 + fm * 16 + l15) * 40 + quad * 8]);
#pragma unroll
        for (int fn = 0; fn < 2; ++fn)
            b[fn] = __builtin_bit_cast(bf16x8, *(const uint4*)&Bs[(wn * 32 + fn * 16 + l15) * 40 + quad * 8]);
#pragma unroll
        for (int fm = 0; fm < 4; ++fm)
#pragma unroll
            for (int fn = 0; fn < 2; ++fn)
                acc[fm][fn] = __builtin_amdgcn_mfma_f32_16x16x32_bf16(a[fm], b[fn], acc[fm][fn], 0, 0, 0);
        __syncthreads();

        ha = nha; hb = nhb;
#pragma unroll
        for (int kk = 0; kk < 8; ++kk) bf[kk] = nbf[kk];
    }

#pragma unroll
    for (int fm = 0; fm < 4; ++fm) {
#pragma unroll
        for (int i = 0; i < 4; ++i) {
            int m_l = wm * 64 + fm * 16 + quad * 4 + i;
            if (m_l < valid) {
                float* orow = out + (size_t)pairs[m_l] * DM + nt * 64 + wn * 32;
#pragma unroll
                for (int fn = 0; fn < 2; ++fn)
                    orow[fn * 16 + l15] = acc[fm][fn][i];
            }
        }
    }
}

extern "C" void kernel_launch(void* const* d_in, const int* in_sizes, int n_in,
                              void* d_out, int out_size, void* d_ws, size_t ws_size,
                              hipStream_t stream) {
    const float* X = (const float*)d_in[0];
    const int* sel = (const int*)d_in[1];
    const float* W1 = (const float*)d_in[3];
    const float* W2 = (const float*)d_in[4];
    float* out = (float*)d_out;
    float* loads_out = out + (size_t)NPAIR * DM;

    int* counts = (int*)d_ws;
    int* cursors = counts + 8;
    int* opad = counts + 16;
    int* rowmap = counts + 32;
    unsigned short* H = (unsigned short*)((char*)d_ws + 65536);

    hipLaunchKernelGGL(k_zero, dim3(1), dim3(64), 0, stream, counts);
    hipLaunchKernelGGL(k_count, dim3(NPAIR / 256), dim3(256), 0, stream, sel, counts);
    hipLaunchKernelGGL(k_scan, dim3(1), dim3(64), 0, stream, counts, opad, loads_out);
    hipLaunchKernelGGL(k_assign, dim3(NPAIR / 256), dim3(256), 0, stream, sel, opad, cursors, rowmap);
    hipLaunchKernelGGL(k_gemm1, dim3(DF / 128, NPAIR / 128, NE), dim3(256), 0, stream,
                       X, W1, counts, opad, rowmap, H);
    hipLaunchKernelGGL(k_gemm2, dim3(DM / 64, NPAIR / 128, NE), dim3(256), 0, stream,
                       H, W2, counts, opad, rowmap, out);
}

// Round 4
// 324.028 us; speedup vs baseline: 1.1825x; 1.0630x over previous
//
#include <hip/hip_runtime.h>
#include <hip/hip_bf16.h>

// ExpertBank MoE FFN on gfx950 — round 4.
// memset(out) -> zero -> count -> scan -> assign -> cvtX -> tw(W1) -> GEMM1 -> tw(W2) -> GEMM2.
// Weights/X pre-converted to bf16 (k-contiguous layouts) so GEMM staging is 2 contiguous
// uint4 loads per thread per iter. gemm2 split-K x4 with fp32 atomics. Fallback to the
// proven round-3 fp32-staging path if ws_size < 58.8 MB.
// ws: int[0..7] counts, [8..15] cursors, [16..23] opad, [32..) rowmap(9216),
//     byte 65536: H bf16 [9216][2048] (37.75 MB), then Xb bf16 [4096][512] (4.2 MB),
//     then WT bf16 [8][2048*512] (16.8 MB, W1T then overwritten by W2T).

typedef __bf16 bf16x8 __attribute__((ext_vector_type(8)));
typedef float f32x4 __attribute__((ext_vector_type(4)));

#define DM 512
#define DF 2048
#define NE 8
#define NTOK 4096
#define NPAIR 8192
#define HCAP 9216

__device__ __forceinline__ unsigned short f2bf(float x) {
    unsigned u = __builtin_bit_cast(unsigned, x);
    return (unsigned short)((u + 0x7fffu + ((u >> 16) & 1u)) >> 16);
}
__device__ __forceinline__ unsigned pack2(float lo, float hi) {
    return (unsigned)f2bf(lo) | ((unsigned)f2bf(hi) << 16);
}
__device__ __forceinline__ float gelu_exact(float x) {
    return 0.5f * x * (1.0f + erff(x * 0.70710678118654752440f));
}

__global__ void k_zero(int* p) {
    if (threadIdx.x < 16) p[threadIdx.x] = 0;
}

__global__ void k_count(const int* __restrict__ sel, int* __restrict__ counts) {
    int p = blockIdx.x * blockDim.x + threadIdx.x;
    if (p < NPAIR) atomicAdd(&counts[sel[p]], 1);
}

__global__ void k_scan(const int* __restrict__ counts, int* __restrict__ opad,
                       float* __restrict__ loads_out) {
    if (threadIdx.x == 0) {
        int s = 0;
        for (int e = 0; e < NE; ++e) {
            opad[e] = s;
            s += (counts[e] + 127) & ~127;
            loads_out[e] = (float)counts[e] * (1.0f / (float)NTOK);
        }
    }
}

__global__ void k_assign(const int* __restrict__ sel, const int* __restrict__ opad,
                         int* __restrict__ cursors, int* __restrict__ rowmap) {
    int p = blockIdx.x * blockDim.x + threadIdx.x;
    if (p < NPAIR) {
        int e = sel[p];
        int pos = atomicAdd(&cursors[e], 1);
        rowmap[opad[e] + pos] = p;
    }
}

// ---- X fp32 -> bf16 (elementwise) ----
__global__ void k_cvtx(const float* __restrict__ X, unsigned short* __restrict__ Xb) {
    int i = (blockIdx.x * 256 + threadIdx.x) * 8;
    float4 a = *(const float4*)(X + i);
    float4 b = *(const float4*)(X + i + 4);
    uint4 u;
    u.x = pack2(a.x, a.y); u.y = pack2(a.z, a.w);
    u.z = pack2(b.x, b.y); u.w = pack2(b.z, b.w);
    *(uint4*)(Xb + i) = u;
}

// ---- W fp32 [E][R][C] -> bf16 transpose [E][C][R], 64x64 LDS tiles ----
__global__ void k_tw(const float* __restrict__ in, unsigned short* __restrict__ out,
                     int R, int C) {
    __shared__ unsigned short T[64][65];
    const int tid = threadIdx.x;
    const int tx = tid & 15, ty = tid >> 4;
    const int r0 = blockIdx.y * 64, c0 = blockIdx.x * 64;
    const float* src = in + ((size_t)blockIdx.z * R + r0) * C + c0;
#pragma unroll
    for (int i = 0; i < 4; ++i) {
        int r = ty + i * 16;
        float4 v = *(const float4*)(src + (size_t)r * C + tx * 4);
        T[tx * 4 + 0][r] = f2bf(v.x); T[tx * 4 + 1][r] = f2bf(v.y);
        T[tx * 4 + 2][r] = f2bf(v.z); T[tx * 4 + 3][r] = f2bf(v.w);
    }
    __syncthreads();
    unsigned short* dst = out + ((size_t)blockIdx.z * C + c0) * R + r0;
#pragma unroll
    for (int i = 0; i < 4; ++i) {
        int c = ty + i * 16;
        ushort4 w;
        w.x = T[c][tx * 4 + 0]; w.y = T[c][tx * 4 + 1];
        w.z = T[c][tx * 4 + 2]; w.w = T[c][tx * 4 + 3];
        *(ushort4*)(dst + (size_t)c * R + tx * 4) = w;
    }
}

// ---------------- GEMM1 (bf16 sources): H = gelu(Xb[tok] @ W1), 128x128, BK=32 -------
__launch_bounds__(256, 3)
__global__ void k_gemm1b(const unsigned short* __restrict__ Xb,
                         const unsigned short* __restrict__ W1T,
                         const int* __restrict__ counts, const int* __restrict__ opad,
                         const int* __restrict__ rowmap, unsigned short* __restrict__ H) {
    const int e = blockIdx.z, mt = blockIdx.y, nt = blockIdx.x;
    const int grow = opad[e] + mt * 128;
    int valid = counts[e] - mt * 128;
    if (valid <= 0) return;
    if (valid > 128) valid = 128;

    __shared__ __align__(16) unsigned short As[128 * 40];
    __shared__ __align__(16) unsigned short Bs[128 * 40];
    __shared__ int toks[128];

    const int tid = threadIdx.x;
    if (tid < 128) {
        int i = (tid < valid) ? tid : 0;
        toks[tid] = rowmap[grow + i] >> 1;
    }
    __syncthreads();

    const int wave = tid >> 6, lane = tid & 63;
    const int wm = wave >> 1, wn = wave & 1;
    const int quad = lane >> 4, l15 = lane & 15;

    f32x4 acc[4][4] = {};

    const int row = tid >> 1, half = tid & 1;
    const unsigned short* ap = Xb + (size_t)toks[row] * DM + half * 16;
    const unsigned short* bp = W1T + ((size_t)e * DF + nt * 128 + row) * DM + half * 16;
    const int lo = row * 40 + half * 16;

    uint4 pa0 = *(const uint4*)ap, pa1 = *(const uint4*)(ap + 8);
    uint4 pb0 = *(const uint4*)bp, pb1 = *(const uint4*)(bp + 8);

    for (int kt = 0; kt < DM / 32; ++kt) {
        *(uint4*)&As[lo] = pa0; *(uint4*)&As[lo + 8] = pa1;
        *(uint4*)&Bs[lo] = pb0; *(uint4*)&Bs[lo + 8] = pb1;
        __syncthreads();
        const int kn = (kt < DM / 32 - 1) ? (kt + 1) * 32 : kt * 32;
        uint4 na0 = *(const uint4*)(ap + kn), na1 = *(const uint4*)(ap + kn + 8);
        uint4 nb0 = *(const uint4*)(bp + kn), nb1 = *(const uint4*)(bp + kn + 8);

        bf16x8 a[4], b[4];
#pragma unroll
        for (int fm = 0; fm < 4; ++fm)
            a[fm] = __builtin_bit_cast(bf16x8, *(const uint4*)&As[(wm * 64 + fm * 16 + l15) * 40 + quad * 8]);
#pragma unroll
        for (int fn = 0; fn < 4; ++fn)
            b[fn] = __builtin_bit_cast(bf16x8, *(const uint4*)&Bs[(wn * 64 + fn * 16 + l15) * 40 + quad * 8]);
#pragma unroll
        for (int fm = 0; fm < 4; ++fm)
#pragma unroll
            for (int fn = 0; fn < 4; ++fn)
                acc[fm][fn] = __builtin_amdgcn_mfma_f32_16x16x32_bf16(a[fm], b[fn], acc[fm][fn], 0, 0, 0);
        __syncthreads();
        pa0 = na0; pa1 = na1; pb0 = nb0; pb1 = nb1;
    }

#pragma unroll
    for (int fm = 0; fm < 4; ++fm) {
#pragma unroll
        for (int i = 0; i < 4; ++i) {
            int m_l = wm * 64 + fm * 16 + quad * 4 + i;
            if (m_l < valid) {
                unsigned short* hrow = H + (size_t)(grow + m_l) * DF + nt * 128 + wn * 64;
#pragma unroll
                for (int fn = 0; fn < 4; ++fn)
                    hrow[fn * 16 + l15] = f2bf(gelu_exact(acc[fm][fn][i]));
            }
        }
    }
}

// ---------------- GEMM2 (bf16 sources): out += H @ W2, 128x128, split-K x4 ----------
__launch_bounds__(256, 3)
__global__ void k_gemm2b(const unsigned short* __restrict__ H,
                         const unsigned short* __restrict__ W2T,
                         const int* __restrict__ counts, const int* __restrict__ opad,
                         const int* __restrict__ rowmap, float* __restrict__ out) {
    const int e = blockIdx.z, mt = blockIdx.y;
    const int nt = blockIdx.x & 3, ks = blockIdx.x >> 2;
    const int grow = opad[e] + mt * 128;
    int valid = counts[e] - mt * 128;
    if (valid <= 0) return;
    if (valid > 128) valid = 128;

    __shared__ __align__(16) unsigned short As[128 * 40];
    __shared__ __align__(16) unsigned short Bs[128 * 40];
    __shared__ int pairs[128];

    const int tid = threadIdx.x;
    if (tid < 128) pairs[tid] = (tid < valid) ? rowmap[grow + tid] : 0;
    __syncthreads();

    const int wave = tid >> 6, lane = tid & 63;
    const int wm = wave >> 1, wn = wave & 1;
    const int quad = lane >> 4, l15 = lane & 15;

    f32x4 acc[4][4] = {};

    const int row = tid >> 1, half = tid & 1;
    const int rr = (row < valid) ? row : 0;
    const unsigned short* ap = H + (size_t)(grow + rr) * DF + ks * 512 + half * 16;
    const unsigned short* bp = W2T + ((size_t)e * DM + nt * 128 + row) * DF + ks * 512 + half * 16;
    const int lo = row * 40 + half * 16;

    uint4 pa0 = *(const uint4*)ap, pa1 = *(const uint4*)(ap + 8);
    uint4 pb0 = *(const uint4*)bp, pb1 = *(const uint4*)(bp + 8);

    for (int kt = 0; kt < 16; ++kt) {
        *(uint4*)&As[lo] = pa0; *(uint4*)&As[lo + 8] = pa1;
        *(uint4*)&Bs[lo] = pb0; *(uint4*)&Bs[lo + 8] = pb1;
        __syncthreads();
        const int kn = (kt < 15) ? (kt + 1) * 32 : kt * 32;
        uint4 na0 = *(const uint4*)(ap + kn), na1 = *(const uint4*)(ap + kn + 8);
        uint4 nb0 = *(const uint4*)(bp + kn), nb1 = *(const uint4*)(bp + kn + 8);

        bf16x8 a[4], b[4];
#pragma unroll
        for (int fm = 0; fm < 4; ++fm)
            a[fm] = __builtin_bit_cast(bf16x8, *(const uint4*)&As[(wm * 64 + fm * 16 + l15) * 40 + quad * 8]);
#pragma unroll
        for (int fn = 0; fn < 4; ++fn)
            b[fn] = __builtin_bit_cast(bf16x8, *(const uint4*)&Bs[(wn * 64 + fn * 16 + l15) * 40 + quad * 8]);
#pragma unroll
        for (int fm = 0; fm < 4; ++fm)
#pragma unroll
            for (int fn = 0; fn < 4; ++fn)
                acc[fm][fn] = __builtin_amdgcn_mfma_f32_16x16x32_bf16(a[fm], b[fn], acc[fm][fn], 0, 0, 0);
        __syncthreads();
        pa0 = na0; pa1 = na1; pb0 = nb0; pb1 = nb1;
    }

#pragma unroll
    for (int fm = 0; fm < 4; ++fm) {
#pragma unroll
        for (int i = 0; i < 4; ++i) {
            int m_l = wm * 64 + fm * 16 + quad * 4 + i;
            if (m_l < valid) {
                float* orow = out + (size_t)pairs[m_l] * DM + nt * 128 + wn * 64;
#pragma unroll
                for (int fn = 0; fn < 4; ++fn)
                    atomicAdd(&orow[fn * 16 + l15], acc[fm][fn][i]);
            }
        }
    }
}

// ================= Fallback (round-3 proven, fp32 staging) =================
__launch_bounds__(256, 3)
__global__ void k_gemm1f(const float* __restrict__ X, const float* __restrict__ W1,
                         const int* __restrict__ counts, const int* __restrict__ opad,
                         const int* __restrict__ rowmap, unsigned short* __restrict__ H) {
    const int e = blockIdx.z, mt = blockIdx.y, nt = blockIdx.x;
    const int grow = opad[e] + mt * 128;
    int valid = counts[e] - mt * 128;
    if (valid <= 0) return;
    if (valid > 128) valid = 128;
    __shared__ __align__(16) unsigned short As[128 * 40];
    __shared__ __align__(16) unsigned short Bs[128 * 40];
    __shared__ int toks[128];
    const int tid = threadIdx.x;
    if (tid < 128) { int i = (tid < valid) ? tid : 0; toks[tid] = rowmap[grow + i] >> 1; }
    __syncthreads();
    const int wave = tid >> 6, lane = tid & 63;
    const int wm = wave >> 1, wn = wave & 1;
    const int quad = lane >> 4, l15 = lane & 15;
    f32x4 acc[4][4] = {};
    const int arow = tid >> 1, ahalf = tid & 1;
    const int bn = tid & 127, bkh = tid >> 7;
    const float* xrow = X + (size_t)toks[arow] * DM + ahalf * 16;
    const float* w1p = W1 + (size_t)e * DM * DF + (size_t)(bkh * 16) * DF + (size_t)(nt * 128 + bn);
    for (int kt = 0; kt < DM / 32; ++kt) {
        const int k0 = kt * 32;
        {
            const float4* s = (const float4*)(xrow + k0);
            float4 v0 = s[0], v1 = s[1], v2 = s[2], v3 = s[3];
            uint4 u0, u1;
            u0.x = pack2(v0.x, v0.y); u0.y = pack2(v0.z, v0.w);
            u0.z = pack2(v1.x, v1.y); u0.w = pack2(v1.z, v1.w);
            u1.x = pack2(v2.x, v2.y); u1.y = pack2(v2.z, v2.w);
            u1.z = pack2(v3.x, v3.y); u1.w = pack2(v3.z, v3.w);
            *(uint4*)&As[arow * 40 + ahalf * 16] = u0;
            *(uint4*)&As[arow * 40 + ahalf * 16 + 8] = u1;
            const float* g = w1p + (size_t)k0 * DF;
            float f[16];
#pragma unroll
            for (int kk = 0; kk < 16; ++kk) f[kk] = g[(size_t)kk * DF];
            uint4 w0, w1v;
            w0.x = pack2(f[0], f[1]);   w0.y = pack2(f[2], f[3]);
            w0.z = pack2(f[4], f[5]);   w0.w = pack2(f[6], f[7]);
            w1v.x = pack2(f[8], f[9]);  w1v.y = pack2(f[10], f[11]);
            w1v.z = pack2(f[12], f[13]); w1v.w = pack2(f[14], f[15]);
            *(uint4*)&Bs[bn * 40 + bkh * 16] = w0;
            *(uint4*)&Bs[bn * 40 + bkh * 16 + 8] = w1v;
        }
        __syncthreads();
        bf16x8 a[4], b[4];
#pragma unroll
        for (int fm = 0; fm < 4; ++fm)
            a[fm] = __builtin_bit_cast(bf16x8, *(const uint4*)&As[(wm * 64 + fm * 16 + l15) * 40 + quad * 8]);
#pragma unroll
        for (int fn = 0; fn < 4; ++fn)
            b[fn] = __builtin_bit_cast(bf16x8, *(const uint4*)&Bs[(wn * 64 + fn * 16 + l15) * 40 + quad * 8]);
#pragma unroll
        for (int fm = 0; fm < 4; ++fm)
#pragma unroll
            for (int fn = 0; fn < 4; ++fn)
                acc[fm][fn] = __builtin_amdgcn_mfma_f32_16x16x32_bf16(a[fm], b[fn], acc[fm][fn], 0, 0, 0);
        __syncthreads();
    }
#pragma unroll
    for (int fm = 0; fm < 4; ++fm)
#pragma unroll
        for (int i = 0; i < 4; ++i) {
            int m_l = wm * 64 + fm * 16 + quad * 4 + i;
            if (m_l < valid) {
                unsigned short* hrow = H + (size_t)(grow + m_l) * DF + nt * 128 + wn * 64;
#pragma unroll
                for (int fn = 0; fn < 4; ++fn)
                    hrow[fn * 16 + l15] = f2bf(gelu_exact(acc[fm][fn][i]));
            }
        }
}

__launch_bounds__(256, 3)
__global__ void k_gemm2f(const unsigned short* __restrict__ H, const float* __restrict__ W2,
                         const int* __restrict__ counts, const int* __restrict__ opad,
                         const int* __restrict__ rowmap, float* __restrict__ out) {
    const int e = blockIdx.z, mt = blockIdx.y, nt = blockIdx.x;
    const int grow = opad[e] + mt * 128;
    int valid = counts[e] - mt * 128;
    if (valid <= 0) return;
    if (valid > 128) valid = 128;
    __shared__ __align__(16) unsigned short As[128 * 40];
    __shared__ __align__(16) unsigned short Bs[64 * 40];
    __shared__ int pairs[128];
    const int tid = threadIdx.x;
    if (tid < 128) pairs[tid] = (tid < valid) ? rowmap[grow + tid] : 0;
    __syncthreads();
    const int wave = tid >> 6, lane = tid & 63;
    const int wm = wave >> 1, wn = wave & 1;
    const int quad = lane >> 4, l15 = lane & 15;
    f32x4 acc[4][2] = {};
    const int ar0 = tid >> 2, sub = tid & 3;
    const int ar1 = ar0 + 64;
    const int rr0 = (ar0 < valid) ? ar0 : 0;
    const int rr1 = (ar1 < valid) ? ar1 : 0;
    const unsigned short* h0 = H + (size_t)(grow + rr0) * DF + sub * 8;
    const unsigned short* h1 = H + (size_t)(grow + rr1) * DF + sub * 8;
    const int bn = tid & 63, bq = tid >> 6;
    const float* w2p = W2 + (size_t)e * DF * DM + (size_t)(bq * 8) * DM + (size_t)(nt * 64 + bn);
    for (int kt = 0; kt < DF / 32; ++kt) {
        const int k0 = kt * 32;
        *(uint4*)&As[ar0 * 40 + sub * 8] = *(const uint4*)(h0 + k0);
        *(uint4*)&As[ar1 * 40 + sub * 8] = *(const uint4*)(h1 + k0);
        {
            const float* g = w2p + (size_t)k0 * DM;
            float f[8];
#pragma unroll
            for (int kk = 0; kk < 8; ++kk) f[kk] = g[(size_t)kk * DM];
            uint4 w;
            w.x = pack2(f[0], f[1]); w.y = pack2(f[2], f[3]);
            w.z = pack2(f[4], f[5]); w.w = pack2(f[6], f[7]);
            *(uint4*)&Bs[bn * 40 + bq * 8] = w;
        }
        __syncthreads();
        bf16x8 a[4], b[2];
#pragma unroll
        for (int fm = 0; fm < 4; ++fm)
            a[fm] = __builtin_bit_cast(bf16x8, *(const uint4*)&As[(wm * 64 + fm * 16 + l15) * 40 + quad * 8]);
#pragma unroll
        for (int fn = 0; fn < 2; ++fn)
            b[fn] = __builtin_bit_cast(bf16x8, *(const uint4*)&Bs[(wn * 32 + fn * 16 + l15) * 40 + quad * 8]);
#pragma unroll
        for (int fm = 0; fm < 4; ++fm)
#pragma unroll
            for (int fn = 0; fn < 2; ++fn)
                acc[fm][fn] = __builtin_amdgcn_mfma_f32_16x16x32_bf16(a[fm], b[fn], acc[fm][fn], 0, 0, 0);
        __syncthreads();
    }
#pragma unroll
    for (int fm = 0; fm < 4; ++fm)
#pragma unroll
        for (int i = 0; i < 4; ++i) {
            int m_l = wm * 64 + fm * 16 + quad * 4 + i;
            if (m_l < valid) {
                float* orow = out + (size_t)pairs[m_l] * DM + nt * 64 + wn * 32;
#pragma unroll
                for (int fn = 0; fn < 2; ++fn)
                    orow[fn * 16 + l15] = acc[fm][fn][i];
            }
        }
}

extern "C" void kernel_launch(void* const* d_in, const int* in_sizes, int n_in,
                              void* d_out, int out_size, void* d_ws, size_t ws_size,
                              hipStream_t stream) {
    const float* X = (const float*)d_in[0];
    const int* sel = (const int*)d_in[1];
    const float* W1 = (const float*)d_in[3];
    const float* W2 = (const float*)d_in[4];
    float* out = (float*)d_out;
    float* loads_out = out + (size_t)NPAIR * DM;

    int* counts = (int*)d_ws;
    int* cursors = counts + 8;
    int* opad = counts + 16;
    int* rowmap = counts + 32;
    const size_t hbytes = (size_t)HCAP * DF * 2;
    const size_t xbytes = (size_t)NTOK * DM * 2;
    const size_t wbytes = (size_t)NE * DM * DF * 2;
    unsigned short* H = (unsigned short*)((char*)d_ws + 65536);
    unsigned short* Xb = (unsigned short*)((char*)d_ws + 65536 + hbytes);
    unsigned short* WT = (unsigned short*)((char*)d_ws + 65536 + hbytes + xbytes);
    const size_t need = 65536 + hbytes + xbytes + wbytes;

    hipMemsetAsync(d_out, 0, (size_t)out_size * sizeof(float), stream);
    hipLaunchKernelGGL(k_zero, dim3(1), dim3(64), 0, stream, counts);
    hipLaunchKernelGGL(k_count, dim3(NPAIR / 256), dim3(256), 0, stream, sel, counts);
    hipLaunchKernelGGL(k_scan, dim3(1), dim3(64), 0, stream, counts, opad, loads_out);
    hipLaunchKernelGGL(k_assign, dim3(NPAIR / 256), dim3(256), 0, stream, sel, opad, cursors, rowmap);

    if (ws_size >= need) {
        hipLaunchKernelGGL(k_cvtx, dim3(NTOK * DM / 2048), dim3(256), 0, stream, X, Xb);
        hipLaunchKernelGGL(k_tw, dim3(DF / 64, DM / 64, NE), dim3(256), 0, stream, W1, WT, DM, DF);
        hipLaunchKernelGGL(k_gemm1b, dim3(DF / 128, NPAIR / 128, NE), dim3(256), 0, stream,
                           Xb, WT, counts, opad, rowmap, H);
        hipLaunchKernelGGL(k_tw, dim3(DM / 64, DF / 64, NE), dim3(256), 0, stream, W2, WT, DF, DM);
        hipLaunchKernelGGL(k_gemm2b, dim3(16, NPAIR / 128, NE), dim3(256), 0, stream,
                           H, WT, counts, opad, rowmap, out);
    } else {
        hipLaunchKernelGGL(k_gemm1f, dim3(DF / 128, NPAIR / 128, NE), dim3(256), 0, stream,
                           X, W1, counts, opad, rowmap, H);
        hipLaunchKernelGGL(k_gemm2f, dim3(DM / 64, NPAIR / 128, NE), dim3(256), 0, stream,
                           H, W2, counts, opad, rowmap, out);
    }
}